// Round 3
// baseline (379.509 us; speedup 1.0000x reference)
//
#include <hip/hip_runtime.h>

typedef _Float16 half8  __attribute__((ext_vector_type(8)));
typedef _Float16 half4  __attribute__((ext_vector_type(4)));
typedef float    f32x4  __attribute__((ext_vector_type(4)));

#define MFMA32(a,b,c) __builtin_amdgcn_mfma_f32_16x16x32_f16(a,b,c,0,0,0)
#define MFMA16(a,b,c) __builtin_amdgcn_mfma_f32_16x16x16f16(a,b,c,0,0,0)

#if __has_builtin(__builtin_amdgcn_exp2f)
#define EXP2F(x) __builtin_amdgcn_exp2f(x)
#else
#define EXP2F(x) exp2f(x)
#endif

// Async global->LDS, 16B/lane, dest = wave-uniform base + lane*16.
// (Only used by k_qkv now; pass1/pass2 stage K/V in registers — the LDS
// round-trip was wave-private there, pure LDS-pipe overhead.)
#define GLOAD16(gp, lp) __builtin_amdgcn_global_load_lds(                      \
    (const __attribute__((address_space(1))) void*)(gp),                       \
    (__attribute__((address_space(3))) void*)(lp), 16, 0, 0)

// scale = DH^-0.5 = 1/8, folded together with log2(e) into Q so softmax uses exp2.
static constexpr float SCALE_LOG2E = 0.18033688011112042f;

static constexpr size_t QH_OFF = 0;
static constexpr size_t KH_OFF = (size_t)8  << 20;
static constexpr size_t VT_OFF = (size_t)16 << 20;
static constexpr size_t LS_OFF = (size_t)24 << 20;
static constexpr size_t O_OFF  = (size_t)25 << 20;
static constexpr size_t LPART  = (size_t)4*8*2048;   // floats per m-half L partial
static constexpr size_t OPART  = (size_t)8192*512;   // halves per O partial
// Xf / Wt f16 staging buffers alias the Obuf region (consumed by k_qkv before
// k_pass2 overwrites it with O partials — stream-ordered, no extra WS).

// G-stride for Sb/Wb: 340 halves = 170 words; l15*10 mod 32 all-distinct.
static constexpr int GS = 340;

// ---------------------------------------------------------------------------
// K0a: X fp32 -> f16.  grid 4096 x 256 threads, 4 elems/thread.
// ---------------------------------------------------------------------------
__global__ __launch_bounds__(256)
void k_cvtx(const float* __restrict__ x, _Float16* __restrict__ xf)
{
  const size_t i = ((size_t)blockIdx.x*256 + threadIdx.x)*4;
  f32x4 v = *(const f32x4*)(x + i);
  half4 h;
#pragma unroll
  for (int j = 0; j < 4; j++) h[j] = (_Float16)v[j];
  *(half4*)(xf + i) = h;
}

// ---------------------------------------------------------------------------
// K0b: W fp32 [512k][1536c] -> f16 transposed Wt [1536c][512k]. LDS-tiled.
// grid (16 k-tiles, 48 c-tiles) x 256 threads.
// ---------------------------------------------------------------------------
__global__ __launch_bounds__(256)
void k_cvtw(const float* __restrict__ w, _Float16* __restrict__ wt)
{
  __shared__ _Float16 T[32][36];
  const int kt = blockIdx.x, ct = blockIdx.y;
  const int r = threadIdx.x >> 3, c4 = (threadIdx.x & 7)*4;
  f32x4 v = *(const f32x4*)(w + (size_t)(kt*32 + r)*1536 + ct*32 + c4);
#pragma unroll
  for (int j = 0; j < 4; j++) T[r][c4 + j] = (_Float16)v[j];
  __syncthreads();
  half4 o;
#pragma unroll
  for (int j = 0; j < 4; j++) o[j] = T[c4 + j][r];
  *(half4*)(wt + (size_t)(ct*32 + r)*512 + kt*32 + c4) = o;
}

// ---------------------------------------------------------------------------
// K1: qkv projection, async-staged all-f16. C[8192,1536] = Xf @ Wt^T + b.
// Per k-step: wave wv stages its 16 X-rows + 16 Wt-rows via GLOAD16 with
// slot swizzle slot(r,o) = r*4 + (o ^ ((r>>1)&3)) (reads ~2-way = free).
// Scatters to Qh (xSCALE_LOG2E), Kh, Vt as before.
// ---------------------------------------------------------------------------
__global__ __launch_bounds__(256)
void k_qkv(const _Float16* __restrict__ xf, const _Float16* __restrict__ wt,
           const float* __restrict__ bias, _Float16* __restrict__ Qh,
           _Float16* __restrict__ Kh, _Float16* __restrict__ Vt)
{
  __shared__ __align__(16) _Float16 Xs[2048];   // 64 rows x 32 k
  __shared__ __align__(16) _Float16 Ws[2048];   // 64 cols x 32 k
  const int tid = threadIdx.x;
  const int wv = tid >> 6, lane = tid & 63, l15 = lane & 15, qd = lane >> 4;
  const int row0 = blockIdx.x * 64, col0 = blockIdx.y * 64;

  // staging address for this lane (slot = wv*64 + lane)
  const int sslot = wv*64 + lane;
  const int sr = sslot >> 2, so = (sslot & 3) ^ ((sr >> 1) & 3);

  f32x4 acc[4] = {{0.f,0.f,0.f,0.f},{0.f,0.f,0.f,0.f},{0.f,0.f,0.f,0.f},{0.f,0.f,0.f,0.f}};

  for (int k0 = 0; k0 < 512; k0 += 32) {
    GLOAD16(xf + (size_t)(row0 + sr)*512 + k0 + so*8, &Xs[wv*512]);
    GLOAD16(wt + (size_t)(col0 + sr)*512 + k0 + so*8, &Ws[wv*512]);
    __syncthreads();
    const int ra = wv*16 + l15;
    half8 af = *(const half8*)&Xs[(ra*4 + (qd ^ ((ra >> 1) & 3)))*8];
#pragma unroll
    for (int ct = 0; ct < 4; ct++) {
      const int rb = ct*16 + l15;
      half8 bf = *(const half8*)&Ws[(rb*4 + (qd ^ ((rb >> 1) & 3)))*8];
      acc[ct] = MFMA32(af, bf, acc[ct]);
    }
    __syncthreads();
  }
#pragma unroll
  for (int ct = 0; ct < 4; ct++) {
    const int c = col0 + ct*16 + l15;
    const int sec = c >> 9, hh = (c >> 6) & 7, d = c & 63;
    const float bv = bias[c];
#pragma unroll
    for (int i = 0; i < 4; i++) {
      const int row = row0 + wv*16 + qd*4 + i;
      const int bb = row >> 11, n = row & 2047;
      float v = acc[ct][i] + bv;
      if (sec == 0)
        Qh[((size_t)((bb*8 + hh)*2048 + n))*64 + d] = (_Float16)(v * SCALE_LOG2E);
      else if (sec == 1)
        Kh[((size_t)((bb*8 + hh)*2048 + n))*64 + d] = (_Float16)v;
      else
        Vt[((size_t)((bb*8 + hh)*64 + d))*2048 + n] = (_Float16)v;
    }
  }
}

// ---------------------------------------------------------------------------
// K2: pass 1 — softmax denominators over an m-half. Grid 512 = 64nt x (4b x 2mh).
// Block = 512 threads (8 waves), 32 n-rows. Sb G-stride 340 (conflict fix).
// K staged directly in registers (wave-private; 1-iter prefetch) — the former
// KB LDS round-trip was pure LDS-pipe overhead.
// ---------------------------------------------------------------------------
__global__ __launch_bounds__(512, 4)
void k_pass1(const _Float16* __restrict__ Qh, const _Float16* __restrict__ Kh,
             const float* __restrict__ th1, float* __restrict__ Lsum)
{
  __shared__ __align__(16) _Float16 Sb[2][2][2704];  // 21632 B
  const int tid = threadIdx.x;
  const int wv = tid >> 6, lane = tid & 63, l15 = lane & 15, qd = lane >> 4;
  const int s = blockIdx.x & 7, nt = blockIdx.x >> 3;
  const int b = s >> 1, mh = s & 1;
  const int n0 = nt << 5;
  const _Float16* kbase = Kh + ((size_t)((b*8 + wv)*2048 + mh*1024))*64;

  half4 a1f;
#pragma unroll
  for (int j = 0; j < 4; j++)
    a1f[j] = ((l15 >> 3) == (qd >> 1)) ? (_Float16)th1[(l15 & 7)*8 + (qd & 1)*4 + j]
                                       : (_Float16)0.f;

  half8 qf[2][2];
#pragma unroll
  for (int t = 0; t < 2; t++) {
    const _Float16* qp = Qh + ((size_t)((b*8 + wv)*2048 + n0 + t*16 + l15))*64 + qd*8;
    qf[t][0] = *(const half8*)qp;
    qf[t][1] = *(const half8*)(qp + 32);
  }

  // direct-to-reg K fragment load: lane (l15,qd) = A-frag row l15, k-group qd
  auto loadK = [&](int it, half8& k0, half8& k1) {
    const _Float16* p = kbase + (size_t)(it*16 + l15)*64 + qd*8;
    k0 = *(const half8*)p;
    k1 = *(const half8*)(p + 32);
  };
  auto qk_to_sb = [&](int buf, half8 ka0, half8 ka1) {
#pragma unroll
    for (int t = 0; t < 2; t++) {
      f32x4 a = {0.f,0.f,0.f,0.f};
      a = MFMA32(ka0, qf[t][0], a);
      a = MFMA32(ka1, qf[t][1], a);
#pragma unroll
      for (int i = 0; i < 4; i++)
        Sb[buf][t][(l15 >> 1)*GS + (qd*4 + i)*20 + wv + 8*(l15 & 1)] = (_Float16)a[i];
    }
  };

  float lacc[2][4];
#pragma unroll
  for (int t = 0; t < 2; t++)
#pragma unroll
    for (int i = 0; i < 4; i++) lacc[t][i] = 0.f;

  half8 kc0, kc1, kn0, kn1;
  loadK(0, kc0, kc1);
  for (int it = 0; it <= 64; it++) {
    if (it + 1 < 64) loadK(it + 1, kn0, kn1);   // 1-iter reg prefetch
    if (it < 64) qk_to_sb(it & 1, kc0, kc1);
    if (it >= 1) {
      const int buf = (it - 1) & 1;
#pragma unroll
      for (int t = 0; t < 2; t++) {
        half4 b1 = *(const half4*)&Sb[buf][t][wv*GS + l15*20 + qd*4];
        f32x4 c1 = MFMA16(a1f, b1, ((f32x4){0.f,0.f,0.f,0.f}));
#pragma unroll
        for (int i = 0; i < 4; i++) lacc[t][i] += EXP2F(c1[i]);
      }
    }
    __syncthreads();
    kc0 = kn0; kc1 = kn1;
  }

#pragma unroll
  for (int t = 0; t < 2; t++)
#pragma unroll
    for (int i = 0; i < 4; i++) {
      float v = lacc[t][i];
      v += __shfl_xor(v, 1); v += __shfl_xor(v, 2);
      v += __shfl_xor(v, 4); v += __shfl_xor(v, 8);
      lacc[t][i] = v;
    }
  if (l15 == 0) {
#pragma unroll
    for (int t = 0; t < 2; t++)
#pragma unroll
      for (int i = 0; i < 4; i++) {
        const int n = n0 + t*16 + wv*2 + (qd >> 1);
        const int g = (qd & 1)*4 + i;
        Lsum[(size_t)mh*LPART + (size_t)(b*8 + g)*2048 + n] = lacc[t][i];
      }
  }
}

// ---------------------------------------------------------------------------
// K3: pass 2 over an m-half. Sb/Wb G-stride 340. K and V now staged directly
// in registers (both were wave-private in LDS): K with a 1-iter prefetch, V
// loaded at iteration top and consumed by PV at the bottom (L2 latency hides
// under QK+th). Removes ~60% of the LDS-pipe traffic (KB/VB reads + the
// global_load_lds write side) — the identified bottleneck.
// ---------------------------------------------------------------------------
__global__ __launch_bounds__(512, 4)
void k_pass2(const _Float16* __restrict__ Qh, const _Float16* __restrict__ Kh,
             const _Float16* __restrict__ Vt, const float* __restrict__ Lsum,
             const float* __restrict__ th1, const float* __restrict__ th2,
             _Float16* __restrict__ Obuf)
{
  __shared__ __align__(16) _Float16 Sb[2][2][2704];  // 21632 B
  __shared__ __align__(16) _Float16 Wb[2][2][2704];  // 21632 B  (total 43264 B)
  const int tid = threadIdx.x;
  const int wv = tid >> 6, lane = tid & 63, l15 = lane & 15, qd = lane >> 4;
  const int s = blockIdx.x & 7, nt = blockIdx.x >> 3;
  const int b = s >> 1, mh = s & 1;
  const int n0 = nt << 5;
  const _Float16* kbase = Kh + ((size_t)((b*8 + wv)*2048 + mh*1024))*64;
  const _Float16* vbase = Vt + (size_t)(b*8 + wv)*64*2048 + mh*1024;

  half4 a1f, b2f;
#pragma unroll
  for (int j = 0; j < 4; j++) {
    const bool diag = ((l15 >> 3) == (qd >> 1));
    a1f[j] = diag ? (_Float16)th1[(l15 & 7)*8 + (qd & 1)*4 + j] : (_Float16)0.f;
    b2f[j] = diag ? (_Float16)th2[(l15 & 7)*8 + (qd & 1)*4 + j] : (_Float16)0.f;
  }

  // softmax seed, hoisted to registers (constant per lane across all iters)
  f32x4 cs[2];
#pragma unroll
  for (int t = 0; t < 2; t++)
#pragma unroll
    for (int i = 0; i < 4; i++) {
      const int n = n0 + t*16 + wv*2 + (qd >> 1);
      const int g = (qd & 1)*4 + i;
      const size_t off = (size_t)(b*8 + g)*2048 + n;
      cs[t][i] = -__log2f(Lsum[off] + Lsum[off + LPART]);
    }

  half8 qf[2][2];
#pragma unroll
  for (int t = 0; t < 2; t++) {
    const _Float16* qp = Qh + ((size_t)((b*8 + wv)*2048 + n0 + t*16 + l15))*64 + qd*8;
    qf[t][0] = *(const half8*)qp;
    qf[t][1] = *(const half8*)(qp + 32);
  }

  auto loadK = [&](int it, half8& k0, half8& k1) {
    const _Float16* p = kbase + (size_t)(it*16 + l15)*64 + qd*8;
    k0 = *(const half8*)p;
    k1 = *(const half8*)(p + 32);
  };
  auto qk_to_sb = [&](int buf, half8 ka0, half8 ka1) {
#pragma unroll
    for (int t = 0; t < 2; t++) {
      f32x4 a = {0.f,0.f,0.f,0.f};
      a = MFMA32(ka0, qf[t][0], a);
      a = MFMA32(ka1, qf[t][1], a);
#pragma unroll
      for (int i = 0; i < 4; i++)
        Sb[buf][t][(l15 >> 1)*GS + (qd*4 + i)*20 + wv + 8*(l15 & 1)] = (_Float16)a[i];
    }
  };

  f32x4 og[2][4];
#pragma unroll
  for (int t = 0; t < 2; t++)
#pragma unroll
    for (int dt = 0; dt < 4; dt++)
      og[t][dt] = (f32x4){0.f,0.f,0.f,0.f};

  half8 kc0, kc1, kn0, kn1;
  loadK(0, kc0, kc1);

  for (int it = 0; it <= 65; it++) {
    if (it + 1 < 64) loadK(it + 1, kn0, kn1);   // K(it+1), used next iter

    // V fragments for this iter's PV (tile it-2): issued early, consumed late.
    // vr[dt] = V[d = dt*16+l15][m_local = 4*qd + j]
    half4 vr[4];
    if (it >= 2) {
#pragma unroll
      for (int dt = 0; dt < 4; dt++)
        vr[dt] = *(const half4*)(vbase + (size_t)(dt*16 + l15)*2048 + (it - 2)*16 + qd*4);
    }

    if (it < 64) qk_to_sb(it & 1, kc0, kc1);

    if (it >= 1 && it <= 64) {
      const int buf = (it - 1) & 1;
#pragma unroll
      for (int t = 0; t < 2; t++) {
        half4 b1 = *(const half4*)&Sb[buf][t][wv*GS + l15*20 + qd*4];
        f32x4 c1 = MFMA16(a1f, b1, cs[t]);
        half4 a2;
#pragma unroll
        for (int i = 0; i < 4; i++) a2[i] = (_Float16)EXP2F(c1[i]);
        f32x4 c2 = MFMA16(a2, b2f, ((f32x4){0.f,0.f,0.f,0.f}));
        half4 w4;
#pragma unroll
        for (int i = 0; i < 4; i++) w4[i] = (_Float16)c2[i];
        *(half4*)&Wb[buf][t][(l15 & 7)*GS + (wv*2 + (l15 >> 3))*20 + qd*4] = w4;
      }
    }
    if (it >= 2) {
      const int buf = (it - 2) & 1;
#pragma unroll
      for (int t = 0; t < 2; t++) {
        half4 af = *(const half4*)&Wb[buf][t][wv*GS + l15*20 + qd*4];
#pragma unroll
        for (int dt = 0; dt < 4; dt++)
          og[t][dt] = MFMA16(af, vr[dt], og[t][dt]);
      }
    }
    __syncthreads();
    kc0 = kn0; kc1 = kn1;
  }

  // epilogue: og[t][dt][i] -> (n = n0+t*16+qd*4+i, col = wv*64 + dt*16 + l15)
  _Float16* Op = Obuf + (size_t)mh * OPART + ((size_t)(b*2048 + n0))*512;
#pragma unroll
  for (int t = 0; t < 2; t++)
#pragma unroll
    for (int dt = 0; dt < 4; dt++)
#pragma unroll
      for (int i = 0; i < 4; i++)
        Op[(size_t)(t*16 + qd*4 + i)*512 + wv*64 + dt*16 + l15] = (_Float16)og[t][dt][i];
}

// ---------------------------------------------------------------------------
// K4: output projection summing 2 partial O buffers.
// out[8192,512] = (O0+O1) @ w_out[512,512] + b_out (fp32 out)
// ---------------------------------------------------------------------------
__global__ __launch_bounds__(256)
void k_oproj(const _Float16* __restrict__ Ob, const float* __restrict__ w,
             const float* __restrict__ bias, float* __restrict__ out)
{
  __shared__ __align__(16) _Float16 Xs[64*40];
  __shared__ __align__(16) _Float16 Wt[64*40];
  const int tid = threadIdx.x;
  const int wv = tid >> 6, lane = tid & 63, l15 = lane & 15, qd = lane >> 4;
  const int row0 = blockIdx.x * 64, col0 = blockIdx.y * 64;
  const int xr = tid >> 2, xc = (tid & 3) * 8;
  const int wk = tid >> 3, wc = (tid & 7) * 8;

  f32x4 acc[4] = {{0.f,0.f,0.f,0.f},{0.f,0.f,0.f,0.f},{0.f,0.f,0.f,0.f},{0.f,0.f,0.f,0.f}};

  for (int k0 = 0; k0 < 512; k0 += 32) {
    const size_t idx = (size_t)(row0 + xr)*512 + k0 + xc;
    half8 a0 = *(const half8*)(Ob + idx);
    half8 a1 = *(const half8*)(Ob + OPART + idx);
    *(half8*)&Xs[xr*40 + xc] = a0 + a1;
    f32x4 b0 = *(const f32x4*)(w + (size_t)(k0 + wk)*512 + col0 + wc);
    f32x4 b1 = *(const f32x4*)(w + (size_t)(k0 + wk)*512 + col0 + wc + 4);
#pragma unroll
    for (int j = 0; j < 4; j++) {
      Wt[(wc+j  )*40 + wk] = (_Float16)b0[j];
      Wt[(wc+j+4)*40 + wk] = (_Float16)b1[j];
    }
    __syncthreads();
    half8 af = *(const half8*)&Xs[(wv*16 + l15)*40 + qd*8];
#pragma unroll
    for (int ct = 0; ct < 4; ct++) {
      half8 bf = *(const half8*)&Wt[(ct*16 + l15)*40 + qd*8];
      acc[ct] = MFMA32(af, bf, acc[ct]);
    }
    __syncthreads();
  }
#pragma unroll
  for (int ct = 0; ct < 4; ct++) {
    const int c = col0 + ct*16 + l15;
    const float bv = bias[c];
#pragma unroll
    for (int i = 0; i < 4; i++) {
      const int row = row0 + wv*16 + qd*4 + i;
      out[(size_t)row*512 + c] = acc[ct][i] + bv;
    }
  }
}

// ---------------------------------------------------------------------------
extern "C" void kernel_launch(void* const* d_in, const int* in_sizes, int n_in,
                              void* d_out, int out_size, void* d_ws, size_t ws_size,
                              hipStream_t stream)
{
  (void)in_sizes; (void)n_in; (void)out_size;
  const float* x     = (const float*)d_in[0];
  const float* w_qkv = (const float*)d_in[1];
  const float* b_qkv = (const float*)d_in[2];
  const float* th1   = (const float*)d_in[3];
  const float* th2   = (const float*)d_in[4];
  const float* w_out = (const float*)d_in[5];
  const float* b_out = (const float*)d_in[6];
  float* out = (float*)d_out;

  char* ws = (char*)d_ws;
  _Float16* Qh   = (_Float16*)(ws + QH_OFF);
  _Float16* Kh   = (_Float16*)(ws + KH_OFF);
  _Float16* Vt   = (_Float16*)(ws + VT_OFF);
  float*    Lsum = (float*)   (ws + LS_OFF);
  _Float16* Obuf = (_Float16*)(ws + O_OFF);
  // Xf/Wt alias the Obuf region (qkv consumes them before pass2 writes O)
  _Float16* Xf   = (_Float16*)(ws + O_OFF);
  _Float16* Wtf  = (_Float16*)(ws + O_OFF + ((size_t)8 << 20));
  if (ws_size < ((size_t)41 << 20)) return;  // need 41 MB scratch

  k_cvtx <<<dim3(4096),    256, 0, stream>>>(x, Xf);
  k_cvtw <<<dim3(16, 48),  256, 0, stream>>>(w_qkv, Wtf);
  k_qkv  <<<dim3(128, 24), 256, 0, stream>>>(Xf, Wtf, b_qkv, Qh, Kh, Vt);
  k_pass1<<<dim3(512),     512, 0, stream>>>(Qh, Kh, th1, Lsum);
  k_pass2<<<dim3(512),     512, 0, stream>>>(Qh, Kh, Vt, Lsum, th1, th2, Obuf);
  k_oproj<<<dim3(128, 8),  256, 0, stream>>>(Obuf, w_out, b_out, out);
}

// Round 6
// 324.157 us; speedup vs baseline: 1.1708x; 1.1708x over previous
//
#include <hip/hip_runtime.h>

typedef _Float16 half8  __attribute__((ext_vector_type(8)));
typedef _Float16 half4  __attribute__((ext_vector_type(4)));
typedef float    f32x4  __attribute__((ext_vector_type(4)));

#define MFMA32(a,b,c) __builtin_amdgcn_mfma_f32_16x16x32_f16(a,b,c,0,0,0)
#define MFMA16(a,b,c) __builtin_amdgcn_mfma_f32_16x16x16f16(a,b,c,0,0,0)

#if __has_builtin(__builtin_amdgcn_exp2f)
#define EXP2F(x) __builtin_amdgcn_exp2f(x)
#else
#define EXP2F(x) exp2f(x)
#endif

// Async global->LDS, 16B/lane, dest = wave-uniform base + lane*16.
// NOTE (round-3 post-mortem): per-lane register staging of K/V doubled L1
// line-transactions and regressed 37%; GLOAD16+LDS redistribute is the
// efficient path for these transposed access patterns. Keep it.
#define GLOAD16(gp, lp) __builtin_amdgcn_global_load_lds(                      \
    (const __attribute__((address_space(1))) void*)(gp),                       \
    (__attribute__((address_space(3))) void*)(lp), 16, 0, 0)

// scale = DH^-0.5 = 1/8, folded together with log2(e) into Q so softmax uses exp2.
static constexpr float SCALE_LOG2E = 0.18033688011112042f;

static constexpr size_t QH_OFF = 0;
static constexpr size_t KH_OFF = (size_t)8  << 20;
static constexpr size_t VT_OFF = (size_t)16 << 20;
static constexpr size_t LS_OFF = (size_t)24 << 20;
static constexpr size_t O_OFF  = (size_t)25 << 20;
static constexpr size_t LPART  = (size_t)4*8*2048;   // floats per m-half L partial
static constexpr size_t OPART  = (size_t)8192*512;   // halves per O partial
// Xf / Wt f16 staging buffers alias the Obuf region (consumed by k_qkv before
// k_pass2 overwrites it with O partials — stream-ordered, no extra WS).

// G-stride for Sb/Wb: 340 halves = 170 words; l15*10 mod 32 all-distinct.
static constexpr int GS = 340;

// ---------------------------------------------------------------------------
// K0a: X fp32 -> f16.  grid 4096 x 256 threads, 4 elems/thread.
// ---------------------------------------------------------------------------
__global__ __launch_bounds__(256)
void k_cvtx(const float* __restrict__ x, _Float16* __restrict__ xf)
{
  const size_t i = ((size_t)blockIdx.x*256 + threadIdx.x)*4;
  f32x4 v = *(const f32x4*)(x + i);
  half4 h;
#pragma unroll
  for (int j = 0; j < 4; j++) h[j] = (_Float16)v[j];
  *(half4*)(xf + i) = h;
}

// ---------------------------------------------------------------------------
// K0b: W fp32 [512k][1536c] -> f16 transposed Wt [1536c][512k]. LDS-tiled.
// grid (16 k-tiles, 48 c-tiles) x 256 threads.
// ---------------------------------------------------------------------------
__global__ __launch_bounds__(256)
void k_cvtw(const float* __restrict__ w, _Float16* __restrict__ wt)
{
  __shared__ _Float16 T[32][36];
  const int kt = blockIdx.x, ct = blockIdx.y;
  const int r = threadIdx.x >> 3, c4 = (threadIdx.x & 7)*4;
  f32x4 v = *(const f32x4*)(w + (size_t)(kt*32 + r)*1536 + ct*32 + c4);
#pragma unroll
  for (int j = 0; j < 4; j++) T[r][c4 + j] = (_Float16)v[j];
  __syncthreads();
  half4 o;
#pragma unroll
  for (int j = 0; j < 4; j++) o[j] = T[c4 + j][r];
  *(half4*)(wt + (size_t)(ct*32 + r)*512 + kt*32 + c4) = o;
}

// ---------------------------------------------------------------------------
// K1: qkv projection, async-staged all-f16. C[8192,1536] = Xf @ Wt^T + b.
// ---------------------------------------------------------------------------
__global__ __launch_bounds__(256)
void k_qkv(const _Float16* __restrict__ xf, const _Float16* __restrict__ wt,
           const float* __restrict__ bias, _Float16* __restrict__ Qh,
           _Float16* __restrict__ Kh, _Float16* __restrict__ Vt)
{
  __shared__ __align__(16) _Float16 Xs[2048];   // 64 rows x 32 k
  __shared__ __align__(16) _Float16 Ws[2048];   // 64 cols x 32 k
  const int tid = threadIdx.x;
  const int wv = tid >> 6, lane = tid & 63, l15 = lane & 15, qd = lane >> 4;
  const int row0 = blockIdx.x * 64, col0 = blockIdx.y * 64;

  // staging address for this lane (slot = wv*64 + lane)
  const int sslot = wv*64 + lane;
  const int sr = sslot >> 2, so = (sslot & 3) ^ ((sr >> 1) & 3);

  f32x4 acc[4] = {{0.f,0.f,0.f,0.f},{0.f,0.f,0.f,0.f},{0.f,0.f,0.f,0.f},{0.f,0.f,0.f,0.f}};

  for (int k0 = 0; k0 < 512; k0 += 32) {
    GLOAD16(xf + (size_t)(row0 + sr)*512 + k0 + so*8, &Xs[wv*512]);
    GLOAD16(wt + (size_t)(col0 + sr)*512 + k0 + so*8, &Ws[wv*512]);
    __syncthreads();
    const int ra = wv*16 + l15;
    half8 af = *(const half8*)&Xs[(ra*4 + (qd ^ ((ra >> 1) & 3)))*8];
#pragma unroll
    for (int ct = 0; ct < 4; ct++) {
      const int rb = ct*16 + l15;
      half8 bf = *(const half8*)&Ws[(rb*4 + (qd ^ ((rb >> 1) & 3)))*8];
      acc[ct] = MFMA32(af, bf, acc[ct]);
    }
    __syncthreads();
  }
#pragma unroll
  for (int ct = 0; ct < 4; ct++) {
    const int c = col0 + ct*16 + l15;
    const int sec = c >> 9, hh = (c >> 6) & 7, d = c & 63;
    const float bv = bias[c];
#pragma unroll
    for (int i = 0; i < 4; i++) {
      const int row = row0 + wv*16 + qd*4 + i;
      const int bb = row >> 11, n = row & 2047;
      float v = acc[ct][i] + bv;
      if (sec == 0)
        Qh[((size_t)((bb*8 + hh)*2048 + n))*64 + d] = (_Float16)(v * SCALE_LOG2E);
      else if (sec == 1)
        Kh[((size_t)((bb*8 + hh)*2048 + n))*64 + d] = (_Float16)v;
      else
        Vt[((size_t)((bb*8 + hh)*64 + d))*2048 + n] = (_Float16)v;
    }
  }
}

// ---------------------------------------------------------------------------
// K2: pass 1 — softmax denominators over an m-half. Grid 512 = 64nt x (4b x 2mh).
// m-loop unrolled x2 (32 m per barrier) — KB[2] subtiles, Sb[2][2]
// (dbuf x sub). Barrier+drain count 66 -> 33. LDS 76032 B -> still
// 2 blocks/CU (grid-capped at 2 anyway).
// ---------------------------------------------------------------------------
__global__ __launch_bounds__(512, 4)
void k_pass1(const _Float16* __restrict__ Qh, const _Float16* __restrict__ Kh,
             const float* __restrict__ th1, float* __restrict__ Lsum)
{
  __shared__ __align__(16) _Float16 KB[2][8][1024];     // 32768 B (2 m-subtiles)
  __shared__ __align__(16) _Float16 Sb[2][2][2][2704];  // 43264 B [buf][sub][t]
  const int tid = threadIdx.x;
  const int wv = tid >> 6, lane = tid & 63, l15 = lane & 15, qd = lane >> 4;
  const int s = blockIdx.x & 7, nt = blockIdx.x >> 3;
  const int b = s >> 1, mh = s & 1;
  const int n0 = nt << 5;
  const _Float16* kbase = Kh + ((size_t)((b*8 + wv)*2048 + mh*1024))*64;

  half4 a1f;
#pragma unroll
  for (int j = 0; j < 4; j++)
    a1f[j] = ((l15 >> 3) == (qd >> 1)) ? (_Float16)th1[(l15 & 7)*8 + (qd & 1)*4 + j]
                                       : (_Float16)0.f;

  half8 qf[2][2];
#pragma unroll
  for (int t = 0; t < 2; t++) {
    const _Float16* qp = Qh + ((size_t)((b*8 + wv)*2048 + n0 + t*16 + l15))*64 + qd*8;
    qf[t][0] = *(const half8*)qp;
    qf[t][1] = *(const half8*)(qp + 32);
  }

  auto issueK = [&](int it, int sub) {
#pragma unroll
    for (int j = 0; j < 2; j++) {
      const int bk = j*64 + lane;
      const int m = bk >> 3, c = bk & 7;
      const int cp = c ^ (m & 7);
      GLOAD16(kbase + (size_t)(it*16 + m)*64 + cp*8, &KB[sub][wv][j*512]);
    }
  };
  auto qk_to_sb = [&](int buf, int sub) {
    half8 ka0 = *(const half8*)&KB[sub][wv][l15*64 + ((qd       ^ (l15 & 7))*8)];
    half8 ka1 = *(const half8*)&KB[sub][wv][l15*64 + (((4 + qd) ^ (l15 & 7))*8)];
#pragma unroll
    for (int t = 0; t < 2; t++) {
      f32x4 a = {0.f,0.f,0.f,0.f};
      a = MFMA32(ka0, qf[t][0], a);
      a = MFMA32(ka1, qf[t][1], a);
#pragma unroll
      for (int i = 0; i < 4; i++)
        Sb[buf][sub][t][(l15 >> 1)*GS + (qd*4 + i)*20 + wv + 8*(l15 & 1)] = (_Float16)a[i];
    }
  };

  float lacc[2][4];
#pragma unroll
  for (int t = 0; t < 2; t++)
#pragma unroll
    for (int i = 0; i < 4; i++) lacc[t][i] = 0.f;

  issueK(0, 0);
  issueK(1, 1);
  __syncthreads();
  for (int ot = 0; ot <= 32; ot++) {
    if (ot < 32) {
      qk_to_sb(ot & 1, 0);          // reads KB[0] (tile 2ot)
      qk_to_sb(ot & 1, 1);          // reads KB[1] (tile 2ot+1)
      if (ot + 1 < 32) {            // in-wave WAR safe vs reads above
        issueK(2*ot + 2, 0);
        issueK(2*ot + 3, 1);
      }
    }
    if (ot >= 1) {
      const int buf = (ot - 1) & 1;
#pragma unroll
      for (int sub = 0; sub < 2; sub++)
#pragma unroll
        for (int t = 0; t < 2; t++) {
          half4 b1 = *(const half4*)&Sb[buf][sub][t][wv*GS + l15*20 + qd*4];
          f32x4 c1 = MFMA16(a1f, b1, ((f32x4){0.f,0.f,0.f,0.f}));
#pragma unroll
          for (int i = 0; i < 4; i++) lacc[t][i] += EXP2F(c1[i]);
        }
    }
    __syncthreads();
  }

#pragma unroll
  for (int t = 0; t < 2; t++)
#pragma unroll
    for (int i = 0; i < 4; i++) {
      float v = lacc[t][i];
      v += __shfl_xor(v, 1); v += __shfl_xor(v, 2);
      v += __shfl_xor(v, 4); v += __shfl_xor(v, 8);
      lacc[t][i] = v;
    }
  if (l15 == 0) {
#pragma unroll
    for (int t = 0; t < 2; t++)
#pragma unroll
      for (int i = 0; i < 4; i++) {
        const int n = n0 + t*16 + wv*2 + (qd >> 1);
        const int g = (qd & 1)*4 + i;
        Lsum[(size_t)mh*LPART + (size_t)(b*8 + g)*2048 + n] = lacc[t][i];
      }
  }
}

// ---------------------------------------------------------------------------
// K3: pass 2 over an m-half (round-0 LDS staging restored).
// Change: vb LDS reads hoisted to iteration top (tile it-2 is valid right
// after the barrier) and issueV(it-1) issued immediately after — V's L2
// latency is covered by the qk+th+PV phases instead of being drained raw at
// the end-of-iteration __syncthreads (vmcnt(0)).
// ---------------------------------------------------------------------------
__global__ __launch_bounds__(512, 4)
void k_pass2(const _Float16* __restrict__ Qh, const _Float16* __restrict__ Kh,
             const _Float16* __restrict__ Vt, const float* __restrict__ Lsum,
             const float* __restrict__ th1, const float* __restrict__ th2,
             _Float16* __restrict__ Obuf)
{
  __shared__ __align__(16) _Float16 KB[8][1024];     // 16384 B
  __shared__ __align__(16) _Float16 VB[8][1024];     // 16384 B [wv][slot=mh*64+d]
  __shared__ __align__(16) _Float16 Sb[2][2][2704];  // 21632 B
  __shared__ __align__(16) _Float16 Wb[2][2][2704];  // 21632 B  (total 76032 B)
  const int tid = threadIdx.x;
  const int wv = tid >> 6, lane = tid & 63, l15 = lane & 15, qd = lane >> 4;
  const int s = blockIdx.x & 7, nt = blockIdx.x >> 3;
  const int b = s >> 1, mh = s & 1;
  const int n0 = nt << 5;
  const _Float16* kbase = Kh + ((size_t)((b*8 + wv)*2048 + mh*1024))*64;
  const _Float16* vbase = Vt + (size_t)(b*8 + wv)*64*2048 + mh*1024;

  half4 a1f, b2f;
#pragma unroll
  for (int j = 0; j < 4; j++) {
    const bool diag = ((l15 >> 3) == (qd >> 1));
    a1f[j] = diag ? (_Float16)th1[(l15 & 7)*8 + (qd & 1)*4 + j] : (_Float16)0.f;
    b2f[j] = diag ? (_Float16)th2[(l15 & 7)*8 + (qd & 1)*4 + j] : (_Float16)0.f;
  }

  // softmax seed, hoisted to registers (constant per lane across all iters)
  f32x4 cs[2];
#pragma unroll
  for (int t = 0; t < 2; t++)
#pragma unroll
    for (int i = 0; i < 4; i++) {
      const int n = n0 + t*16 + wv*2 + (qd >> 1);
      const int g = (qd & 1)*4 + i;
      const size_t off = (size_t)(b*8 + g)*2048 + n;
      cs[t][i] = -__log2f(Lsum[off] + Lsum[off + LPART]);
    }

  half8 qf[2][2];
#pragma unroll
  for (int t = 0; t < 2; t++) {
    const _Float16* qp = Qh + ((size_t)((b*8 + wv)*2048 + n0 + t*16 + l15))*64 + qd*8;
    qf[t][0] = *(const half8*)qp;
    qf[t][1] = *(const half8*)(qp + 32);
  }

  auto issueK = [&](int it) {
#pragma unroll
    for (int j = 0; j < 2; j++) {
      const int bk = j*64 + lane;
      const int m = bk >> 3, c = bk & 7;
      const int cp = c ^ (m & 7);
      GLOAD16(kbase + (size_t)(it*16 + m)*64 + cp*8, &KB[wv][j*512]);
    }
  };
  // VB slots: issue j covers slots j*64+lane = (mhalf=j, d=lane)
  auto issueV = [&](int it) {
#pragma unroll
    for (int j = 0; j < 2; j++)
      GLOAD16(vbase + (size_t)lane*2048 + it*16 + j*8, &VB[wv][j*512]);
  };
  auto qk_to_sb = [&](int buf) {
    half8 ka0 = *(const half8*)&KB[wv][l15*64 + ((qd       ^ (l15 & 7))*8)];
    half8 ka1 = *(const half8*)&KB[wv][l15*64 + (((4 + qd) ^ (l15 & 7))*8)];
#pragma unroll
    for (int t = 0; t < 2; t++) {
      f32x4 a = {0.f,0.f,0.f,0.f};
      a = MFMA32(ka0, qf[t][0], a);
      a = MFMA32(ka1, qf[t][1], a);
#pragma unroll
      for (int i = 0; i < 4; i++)
        Sb[buf][t][(l15 >> 1)*GS + (qd*4 + i)*20 + wv + 8*(l15 & 1)] = (_Float16)a[i];
    }
  };

  f32x4 og[2][4];
#pragma unroll
  for (int t = 0; t < 2; t++)
#pragma unroll
    for (int dt = 0; dt < 4; dt++)
      og[t][dt] = (f32x4){0.f,0.f,0.f,0.f};

  issueK(0);
  __syncthreads();

  for (int it = 0; it <= 65; it++) {
    // --- V fragment reads for this iter's PV (tile it-2): staged during
    // it-1, valid right after the barrier. Read FIRST, then re-issue V.
    half4 vb[4];
    if (it >= 2) {
#pragma unroll
      for (int dt = 0; dt < 4; dt++)
        vb[dt] = *(const half4*)&VB[wv][((qd >> 1)*64 + dt*16 + l15)*8 + (qd & 1)*4];
    }
    // issue V(it-1) early: its latency is covered by qk+th+PV below, so the
    // barrier's vmcnt(0) drain no longer eats V's full L2 latency.
    if (it >= 1 && it <= 64) issueV(it - 1);   // in-wave WAR safe vs reads above

    if (it < 64) {
      qk_to_sb(it & 1);
      if (it + 1 < 64) issueK(it + 1);
    }

    if (it >= 1 && it <= 64) {
      const int buf = (it - 1) & 1;
#pragma unroll
      for (int t = 0; t < 2; t++) {
        half4 b1 = *(const half4*)&Sb[buf][t][wv*GS + l15*20 + qd*4];
        f32x4 c1 = MFMA16(a1f, b1, cs[t]);
        half4 a2;
#pragma unroll
        for (int i = 0; i < 4; i++) a2[i] = (_Float16)EXP2F(c1[i]);
        f32x4 c2 = MFMA16(a2, b2f, ((f32x4){0.f,0.f,0.f,0.f}));
        half4 w4;
#pragma unroll
        for (int i = 0; i < 4; i++) w4[i] = (_Float16)c2[i];
        *(half4*)&Wb[buf][t][(l15 & 7)*GS + (wv*2 + (l15 >> 3))*20 + qd*4] = w4;
      }
    }
    if (it >= 2) {
      const int buf = (it - 2) & 1;
#pragma unroll
      for (int t = 0; t < 2; t++) {
        half4 af = *(const half4*)&Wb[buf][t][wv*GS + l15*20 + qd*4];
#pragma unroll
        for (int dt = 0; dt < 4; dt++)
          og[t][dt] = MFMA16(af, vb[dt], og[t][dt]);
      }
    }
    __syncthreads();
  }

  // epilogue: og[t][dt][i] -> (n = n0+t*16+qd*4+i, col = wv*64 + dt*16 + l15)
  _Float16* Op = Obuf + (size_t)mh * OPART + ((size_t)(b*2048 + n0))*512;
#pragma unroll
  for (int t = 0; t < 2; t++)
#pragma unroll
    for (int dt = 0; dt < 4; dt++)
#pragma unroll
      for (int i = 0; i < 4; i++)
        Op[(size_t)(t*16 + qd*4 + i)*512 + wv*64 + dt*16 + l15] = (_Float16)og[t][dt][i];
}

// ---------------------------------------------------------------------------
// K4: output projection summing 2 partial O buffers.
// out[8192,512] = (O0+O1) @ w_out[512,512] + b_out (fp32 out)
// ---------------------------------------------------------------------------
__global__ __launch_bounds__(256)
void k_oproj(const _Float16* __restrict__ Ob, const float* __restrict__ w,
             const float* __restrict__ bias, float* __restrict__ out)
{
  __shared__ __align__(16) _Float16 Xs[64*40];
  __shared__ __align__(16) _Float16 Wt[64*40];
  const int tid = threadIdx.x;
  const int wv = tid >> 6, lane = tid & 63, l15 = lane & 15, qd = lane >> 4;
  const int row0 = blockIdx.x * 64, col0 = blockIdx.y * 64;
  const int xr = tid >> 2, xc = (tid & 3) * 8;
  const int wk = tid >> 3, wc = (tid & 7) * 8;

  f32x4 acc[4] = {{0.f,0.f,0.f,0.f},{0.f,0.f,0.f,0.f},{0.f,0.f,0.f,0.f},{0.f,0.f,0.f,0.f}};

  for (int k0 = 0; k0 < 512; k0 += 32) {
    const size_t idx = (size_t)(row0 + xr)*512 + k0 + xc;
    half8 a0 = *(const half8*)(Ob + idx);
    half8 a1 = *(const half8*)(Ob + OPART + idx);
    *(half8*)&Xs[xr*40 + xc] = a0 + a1;
    f32x4 b0 = *(const f32x4*)(w + (size_t)(k0 + wk)*512 + col0 + wc);
    f32x4 b1 = *(const f32x4*)(w + (size_t)(k0 + wk)*512 + col0 + wc + 4);
#pragma unroll
    for (int j = 0; j < 4; j++) {
      Wt[(wc+j  )*40 + wk] = (_Float16)b0[j];
      Wt[(wc+j+4)*40 + wk] = (_Float16)b1[j];
    }
    __syncthreads();
    half8 af = *(const half8*)&Xs[(wv*16 + l15)*40 + qd*8];
#pragma unroll
    for (int ct = 0; ct < 4; ct++) {
      half8 bf = *(const half8*)&Wt[(ct*16 + l15)*40 + qd*8];
      acc[ct] = MFMA32(af, bf, acc[ct]);
    }
    __syncthreads();
  }
#pragma unroll
  for (int ct = 0; ct < 4; ct++) {
    const int c = col0 + ct*16 + l15;
    const float bv = bias[c];
#pragma unroll
    for (int i = 0; i < 4; i++) {
      const int row = row0 + wv*16 + qd*4 + i;
      out[(size_t)row*512 + c] = acc[ct][i] + bv;
    }
  }
}

// ---------------------------------------------------------------------------
extern "C" void kernel_launch(void* const* d_in, const int* in_sizes, int n_in,
                              void* d_out, int out_size, void* d_ws, size_t ws_size,
                              hipStream_t stream)
{
  (void)in_sizes; (void)n_in; (void)out_size;
  const float* x     = (const float*)d_in[0];
  const float* w_qkv = (const float*)d_in[1];
  const float* b_qkv = (const float*)d_in[2];
  const float* th1   = (const float*)d_in[3];
  const float* th2   = (const float*)d_in[4];
  const float* w_out = (const float*)d_in[5];
  const float* b_out = (const float*)d_in[6];
  float* out = (float*)d_out;

  char* ws = (char*)d_ws;
  _Float16* Qh   = (_Float16*)(ws + QH_OFF);
  _Float16* Kh   = (_Float16*)(ws + KH_OFF);
  _Float16* Vt   = (_Float16*)(ws + VT_OFF);
  float*    Lsum = (float*)   (ws + LS_OFF);
  _Float16* Obuf = (_Float16*)(ws + O_OFF);
  // Xf/Wt alias the Obuf region (qkv consumes them before pass2 writes O)
  _Float16* Xf   = (_Float16*)(ws + O_OFF);
  _Float16* Wtf  = (_Float16*)(ws + O_OFF + ((size_t)8 << 20));
  if (ws_size < ((size_t)41 << 20)) return;  // need 41 MB scratch

  k_cvtx <<<dim3(4096),    256, 0, stream>>>(x, Xf);
  k_cvtw <<<dim3(16, 48),  256, 0, stream>>>(w_qkv, Wtf);
  k_qkv  <<<dim3(128, 24), 256, 0, stream>>>(Xf, Wtf, b_qkv, Qh, Kh, Vt);
  k_pass1<<<dim3(512),     512, 0, stream>>>(Qh, Kh, th1, Lsum);
  k_pass2<<<dim3(512),     512, 0, stream>>>(Qh, Kh, Vt, Lsum, th1, th2, Obuf);
  k_oproj<<<dim3(128, 8),  256, 0, stream>>>(Obuf, w_out, b_out, out);
}

// Round 8
// 298.555 us; speedup vs baseline: 1.2712x; 1.0858x over previous
//
#include <hip/hip_runtime.h>

typedef _Float16 half8  __attribute__((ext_vector_type(8)));
typedef _Float16 half4  __attribute__((ext_vector_type(4)));
typedef float    f32x4  __attribute__((ext_vector_type(4)));

#define MFMA32(a,b,c) __builtin_amdgcn_mfma_f32_16x16x32_f16(a,b,c,0,0,0)
#define MFMA16(a,b,c) __builtin_amdgcn_mfma_f32_16x16x16f16(a,b,c,0,0,0)

#if __has_builtin(__builtin_amdgcn_exp2f)
#define EXP2F(x) __builtin_amdgcn_exp2f(x)
#else
#define EXP2F(x) exp2f(x)
#endif

// Async global->LDS, 16B/lane, dest = wave-uniform base + lane*16.
// (round-3 post-mortem: per-lane reg staging of K/V doubled L1 transactions,
// -37%; GLOAD16+LDS redistribute is the right transport here.)
#define GLOAD16(gp, lp) __builtin_amdgcn_global_load_lds(                      \
    (const __attribute__((address_space(1))) void*)(gp),                       \
    (__attribute__((address_space(3))) void*)(lp), 16, 0, 0)

// scale = DH^-0.5 = 1/8, folded together with log2(e) into Q so softmax uses exp2.
static constexpr float SCALE_LOG2E = 0.18033688011112042f;

static constexpr size_t QH_OFF = 0;
static constexpr size_t KH_OFF = (size_t)8  << 20;
static constexpr size_t VT_OFF = (size_t)16 << 20;
static constexpr size_t LS_OFF = (size_t)24 << 20;
static constexpr size_t O_OFF  = (size_t)25 << 20;
static constexpr size_t LPART  = (size_t)4*8*2048;   // floats per m-half L partial
static constexpr size_t OPART  = (size_t)8192*512;   // halves per O partial

// Sb layout [A=n>>1][s=h+8*np][C=m]: GS=340 (A stride), 20 (s stride), C unit.
// SWAPPED vs the old [A][C][s]: the QK->Sb write is now a single b64 per t
// (i-contiguous, 8B-aligned, self-balancing banks) and the th-phase read is
// 8x b16 at banks 8*qd + (l15>>1) + const -> all-32-distinct, conflict-free,
// adjacent lanes word-share. Old layout's 8x b16 scatter was 4-way conflicted
// (even-bank lattice) = the measured 1.68e7 SQ_LDS_BANK_CONFLICT.
// Wb keeps the old [A][C][s]-style layout (both sides already b64, floor-bound).
static constexpr int GS = 340;

// ---------------------------------------------------------------------------
// K0a: X fp32 -> f16.  grid 4096 x 256 threads, 4 elems/thread.
// ---------------------------------------------------------------------------
__global__ __launch_bounds__(256)
void k_cvtx(const float* __restrict__ x, _Float16* __restrict__ xf)
{
  const size_t i = ((size_t)blockIdx.x*256 + threadIdx.x)*4;
  f32x4 v = *(const f32x4*)(x + i);
  half4 h;
#pragma unroll
  for (int j = 0; j < 4; j++) h[j] = (_Float16)v[j];
  *(half4*)(xf + i) = h;
}

// ---------------------------------------------------------------------------
// K0b: W fp32 [512k][1536c] -> f16 transposed Wt [1536c][512k]. LDS-tiled.
// ---------------------------------------------------------------------------
__global__ __launch_bounds__(256)
void k_cvtw(const float* __restrict__ w, _Float16* __restrict__ wt)
{
  __shared__ _Float16 T[32][36];
  const int kt = blockIdx.x, ct = blockIdx.y;
  const int r = threadIdx.x >> 3, c4 = (threadIdx.x & 7)*4;
  f32x4 v = *(const f32x4*)(w + (size_t)(kt*32 + r)*1536 + ct*32 + c4);
#pragma unroll
  for (int j = 0; j < 4; j++) T[r][c4 + j] = (_Float16)v[j];
  __syncthreads();
  half4 o;
#pragma unroll
  for (int j = 0; j < 4; j++) o[j] = T[c4 + j][r];
  *(half4*)(wt + (size_t)(ct*32 + r)*512 + kt*32 + c4) = o;
}

// ---------------------------------------------------------------------------
// K1: qkv projection, async-staged all-f16. C[8192,1536] = Xf @ Wt^T + b.
// ---------------------------------------------------------------------------
__global__ __launch_bounds__(256)
void k_qkv(const _Float16* __restrict__ xf, const _Float16* __restrict__ wt,
           const float* __restrict__ bias, _Float16* __restrict__ Qh,
           _Float16* __restrict__ Kh, _Float16* __restrict__ Vt)
{
  __shared__ __align__(16) _Float16 Xs[2048];   // 64 rows x 32 k
  __shared__ __align__(16) _Float16 Ws[2048];   // 64 cols x 32 k
  const int tid = threadIdx.x;
  const int wv = tid >> 6, lane = tid & 63, l15 = lane & 15, qd = lane >> 4;
  const int row0 = blockIdx.x * 64, col0 = blockIdx.y * 64;

  const int sslot = wv*64 + lane;
  const int sr = sslot >> 2, so = (sslot & 3) ^ ((sr >> 1) & 3);

  f32x4 acc[4] = {{0.f,0.f,0.f,0.f},{0.f,0.f,0.f,0.f},{0.f,0.f,0.f,0.f},{0.f,0.f,0.f,0.f}};

  for (int k0 = 0; k0 < 512; k0 += 32) {
    GLOAD16(xf + (size_t)(row0 + sr)*512 + k0 + so*8, &Xs[wv*512]);
    GLOAD16(wt + (size_t)(col0 + sr)*512 + k0 + so*8, &Ws[wv*512]);
    __syncthreads();
    const int ra = wv*16 + l15;
    half8 af = *(const half8*)&Xs[(ra*4 + (qd ^ ((ra >> 1) & 3)))*8];
#pragma unroll
    for (int ct = 0; ct < 4; ct++) {
      const int rb = ct*16 + l15;
      half8 bf = *(const half8*)&Ws[(rb*4 + (qd ^ ((rb >> 1) & 3)))*8];
      acc[ct] = MFMA32(af, bf, acc[ct]);
    }
    __syncthreads();
  }
#pragma unroll
  for (int ct = 0; ct < 4; ct++) {
    const int c = col0 + ct*16 + l15;
    const int sec = c >> 9, hh = (c >> 6) & 7, d = c & 63;
    const float bv = bias[c];
#pragma unroll
    for (int i = 0; i < 4; i++) {
      const int row = row0 + wv*16 + qd*4 + i;
      const int bb = row >> 11, n = row & 2047;
      float v = acc[ct][i] + bv;
      if (sec == 0)
        Qh[((size_t)((bb*8 + hh)*2048 + n))*64 + d] = (_Float16)(v * SCALE_LOG2E);
      else if (sec == 1)
        Kh[((size_t)((bb*8 + hh)*2048 + n))*64 + d] = (_Float16)v;
      else
        Vt[((size_t)((bb*8 + hh)*64 + d))*2048 + n] = (_Float16)v;
    }
  }
}

// ---------------------------------------------------------------------------
// K2: pass 1 — softmax denominators over an m-half. Grid 512 = 64nt x (4b x 2mh).
// Round-0 structure + swapped Sb layout (see GS comment above).
// ---------------------------------------------------------------------------
__global__ __launch_bounds__(512, 4)
void k_pass1(const _Float16* __restrict__ Qh, const _Float16* __restrict__ Kh,
             const float* __restrict__ th1, float* __restrict__ Lsum)
{
  __shared__ __align__(16) _Float16 KB[8][1024];     // 16384 B
  __shared__ __align__(16) _Float16 Sb[2][2][2704];  // 21632 B
  const int tid = threadIdx.x;
  const int wv = tid >> 6, lane = tid & 63, l15 = lane & 15, qd = lane >> 4;
  const int s = blockIdx.x & 7, nt = blockIdx.x >> 3;
  const int b = s >> 1, mh = s & 1;
  const int n0 = nt << 5;
  const _Float16* kbase = Kh + ((size_t)((b*8 + wv)*2048 + mh*1024))*64;

  half4 a1f;
#pragma unroll
  for (int j = 0; j < 4; j++)
    a1f[j] = ((l15 >> 3) == (qd >> 1)) ? (_Float16)th1[(l15 & 7)*8 + (qd & 1)*4 + j]
                                       : (_Float16)0.f;

  half8 qf[2][2];
#pragma unroll
  for (int t = 0; t < 2; t++) {
    const _Float16* qp = Qh + ((size_t)((b*8 + wv)*2048 + n0 + t*16 + l15))*64 + qd*8;
    qf[t][0] = *(const half8*)qp;
    qf[t][1] = *(const half8*)(qp + 32);
  }

  auto issueK = [&](int it) {
#pragma unroll
    for (int j = 0; j < 2; j++) {
      const int bk = j*64 + lane;
      const int m = bk >> 3, c = bk & 7;
      const int cp = c ^ (m & 7);
      GLOAD16(kbase + (size_t)(it*16 + m)*64 + cp*8, &KB[wv][j*512]);
    }
  };
  // swapped layout: one b64 write per t at [A=l15>>1][s=wv+8*(l15&1)][C=qd*4]
  auto qk_to_sb = [&](int buf) {
    half8 ka0 = *(const half8*)&KB[wv][l15*64 + ((qd       ^ (l15 & 7))*8)];
    half8 ka1 = *(const half8*)&KB[wv][l15*64 + (((4 + qd) ^ (l15 & 7))*8)];
#pragma unroll
    for (int t = 0; t < 2; t++) {
      f32x4 a = {0.f,0.f,0.f,0.f};
      a = MFMA32(ka0, qf[t][0], a);
      a = MFMA32(ka1, qf[t][1], a);
      half4 s4;
#pragma unroll
      for (int i = 0; i < 4; i++) s4[i] = (_Float16)a[i];
      *(half4*)&Sb[buf][t][(l15 >> 1)*GS + (wv + 8*(l15 & 1))*20 + qd*4] = s4;
    }
  };

  float lacc[2][4];
#pragma unroll
  for (int t = 0; t < 2; t++)
#pragma unroll
    for (int i = 0; i < 4; i++) lacc[t][i] = 0.f;

  issueK(0);
  __syncthreads();
  for (int it = 0; it <= 64; it++) {
    if (it < 64) {
      qk_to_sb(it & 1);
      if (it + 1 < 64) issueK(it + 1);
    }
    if (it >= 1) {
      const int buf = (it - 1) & 1;
#pragma unroll
      for (int t = 0; t < 2; t++) {
        half4 b1;
#pragma unroll
        for (int j = 0; j < 4; j++)
          b1[j] = Sb[buf][t][wv*GS + (qd*4 + j)*20 + l15];
        f32x4 c1 = MFMA16(a1f, b1, ((f32x4){0.f,0.f,0.f,0.f}));
#pragma unroll
        for (int i = 0; i < 4; i++) lacc[t][i] += EXP2F(c1[i]);
      }
    }
    __syncthreads();
  }

#pragma unroll
  for (int t = 0; t < 2; t++)
#pragma unroll
    for (int i = 0; i < 4; i++) {
      float v = lacc[t][i];
      v += __shfl_xor(v, 1); v += __shfl_xor(v, 2);
      v += __shfl_xor(v, 4); v += __shfl_xor(v, 8);
      lacc[t][i] = v;
    }
  if (l15 == 0) {
#pragma unroll
    for (int t = 0; t < 2; t++)
#pragma unroll
      for (int i = 0; i < 4; i++) {
        const int n = n0 + t*16 + wv*2 + (qd >> 1);
        const int g = (qd & 1)*4 + i;
        Lsum[(size_t)mh*LPART + (size_t)(b*8 + g)*2048 + n] = lacc[t][i];
      }
  }
}

// ---------------------------------------------------------------------------
// K3: pass 2 over an m-half. Round-0 structure (140us verified) + swapped Sb
// layout. Wb unchanged (b64 both sides, floor-bound banks).
// ---------------------------------------------------------------------------
__global__ __launch_bounds__(512, 4)
void k_pass2(const _Float16* __restrict__ Qh, const _Float16* __restrict__ Kh,
             const _Float16* __restrict__ Vt, const float* __restrict__ Lsum,
             const float* __restrict__ th1, const float* __restrict__ th2,
             _Float16* __restrict__ Obuf)
{
  __shared__ __align__(16) _Float16 KB[8][1024];     // 16384 B
  __shared__ __align__(16) _Float16 VB[8][1024];     // 16384 B [wv][slot=mh2*64+d]
  __shared__ __align__(16) _Float16 Sb[2][2][2704];  // 21632 B
  __shared__ __align__(16) _Float16 Wb[2][2][2704];  // 21632 B  (total 76032 B)
  const int tid = threadIdx.x;
  const int wv = tid >> 6, lane = tid & 63, l15 = lane & 15, qd = lane >> 4;
  const int s = blockIdx.x & 7, nt = blockIdx.x >> 3;
  const int b = s >> 1, mh = s & 1;
  const int n0 = nt << 5;
  const _Float16* kbase = Kh + ((size_t)((b*8 + wv)*2048 + mh*1024))*64;
  const _Float16* vbase = Vt + (size_t)(b*8 + wv)*64*2048 + mh*1024;

  half4 a1f, b2f;
#pragma unroll
  for (int j = 0; j < 4; j++) {
    const bool diag = ((l15 >> 3) == (qd >> 1));
    a1f[j] = diag ? (_Float16)th1[(l15 & 7)*8 + (qd & 1)*4 + j] : (_Float16)0.f;
    b2f[j] = diag ? (_Float16)th2[(l15 & 7)*8 + (qd & 1)*4 + j] : (_Float16)0.f;
  }

  // softmax seed, hoisted to registers (constant per lane across all iters)
  f32x4 cs[2];
#pragma unroll
  for (int t = 0; t < 2; t++)
#pragma unroll
    for (int i = 0; i < 4; i++) {
      const int n = n0 + t*16 + wv*2 + (qd >> 1);
      const int g = (qd & 1)*4 + i;
      const size_t off = (size_t)(b*8 + g)*2048 + n;
      cs[t][i] = -__log2f(Lsum[off] + Lsum[off + LPART]);
    }

  half8 qf[2][2];
#pragma unroll
  for (int t = 0; t < 2; t++) {
    const _Float16* qp = Qh + ((size_t)((b*8 + wv)*2048 + n0 + t*16 + l15))*64 + qd*8;
    qf[t][0] = *(const half8*)qp;
    qf[t][1] = *(const half8*)(qp + 32);
  }

  auto issueK = [&](int it) {
#pragma unroll
    for (int j = 0; j < 2; j++) {
      const int bk = j*64 + lane;
      const int m = bk >> 3, c = bk & 7;
      const int cp = c ^ (m & 7);
      GLOAD16(kbase + (size_t)(it*16 + m)*64 + cp*8, &KB[wv][j*512]);
    }
  };
  // VB slots: issue j covers slots j*64+lane = (mhalf=j, d=lane)
  auto issueV = [&](int it) {
#pragma unroll
    for (int j = 0; j < 2; j++)
      GLOAD16(vbase + (size_t)lane*2048 + it*16 + j*8, &VB[wv][j*512]);
  };
  // swapped layout: one b64 write per t (see k_pass1)
  auto qk_to_sb = [&](int buf) {
    half8 ka0 = *(const half8*)&KB[wv][l15*64 + ((qd       ^ (l15 & 7))*8)];
    half8 ka1 = *(const half8*)&KB[wv][l15*64 + (((4 + qd) ^ (l15 & 7))*8)];
#pragma unroll
    for (int t = 0; t < 2; t++) {
      f32x4 a = {0.f,0.f,0.f,0.f};
      a = MFMA32(ka0, qf[t][0], a);
      a = MFMA32(ka1, qf[t][1], a);
      half4 s4;
#pragma unroll
      for (int i = 0; i < 4; i++) s4[i] = (_Float16)a[i];
      *(half4*)&Sb[buf][t][(l15 >> 1)*GS + (wv + 8*(l15 & 1))*20 + qd*4] = s4;
    }
  };

  f32x4 og[2][4];
#pragma unroll
  for (int t = 0; t < 2; t++)
#pragma unroll
    for (int dt = 0; dt < 4; dt++)
      og[t][dt] = (f32x4){0.f,0.f,0.f,0.f};

  issueK(0);
  __syncthreads();

  for (int it = 0; it <= 65; it++) {
    if (it < 64) {
      qk_to_sb(it & 1);
      if (it + 1 < 64) issueK(it + 1);
    }

    if (it >= 1 && it <= 64) {
      const int buf = (it - 1) & 1;
#pragma unroll
      for (int t = 0; t < 2; t++) {
        half4 b1;
#pragma unroll
        for (int j = 0; j < 4; j++)
          b1[j] = Sb[buf][t][wv*GS + (qd*4 + j)*20 + l15];
        f32x4 c1 = MFMA16(a1f, b1, cs[t]);
        half4 a2;
#pragma unroll
        for (int i = 0; i < 4; i++) a2[i] = (_Float16)EXP2F(c1[i]);
        f32x4 c2 = MFMA16(a2, b2f, ((f32x4){0.f,0.f,0.f,0.f}));
        half4 w4;
#pragma unroll
        for (int i = 0; i < 4; i++) w4[i] = (_Float16)c2[i];
        *(half4*)&Wb[buf][t][(l15 & 7)*GS + (wv*2 + (l15 >> 3))*20 + qd*4] = w4;
      }
    }
    if (it >= 2) {
      const int buf = (it - 2) & 1;
      half4 vb[4];
#pragma unroll
      for (int dt = 0; dt < 4; dt++)
        vb[dt] = *(const half4*)&VB[wv][((qd >> 1)*64 + dt*16 + l15)*8 + (qd & 1)*4];
#pragma unroll
      for (int t = 0; t < 2; t++) {
        half4 af = *(const half4*)&Wb[buf][t][wv*GS + l15*20 + qd*4];
#pragma unroll
        for (int dt = 0; dt < 4; dt++)
          og[t][dt] = MFMA16(af, vb[dt], og[t][dt]);
      }
    }
    if (it >= 1 && it <= 64) issueV(it - 1);   // after VB reads (in-wave WAR safe)
    __syncthreads();
  }

  // epilogue: og[t][dt][i] -> (n = n0+t*16+qd*4+i, col = wv*64 + dt*16 + l15)
  _Float16* Op = Obuf + (size_t)mh * OPART + ((size_t)(b*2048 + n0))*512;
#pragma unroll
  for (int t = 0; t < 2; t++)
#pragma unroll
    for (int dt = 0; dt < 4; dt++)
#pragma unroll
      for (int i = 0; i < 4; i++)
        Op[(size_t)(t*16 + qd*4 + i)*512 + wv*64 + dt*16 + l15] = (_Float16)og[t][dt][i];
}

// ---------------------------------------------------------------------------
// K4: output projection summing 2 partial O buffers.
// out[8192,512] = (O0+O1) @ w_out[512,512] + b_out (fp32 out)
// ---------------------------------------------------------------------------
__global__ __launch_bounds__(256)
void k_oproj(const _Float16* __restrict__ Ob, const float* __restrict__ w,
             const float* __restrict__ bias, float* __restrict__ out)
{
  __shared__ __align__(16) _Float16 Xs[64*40];
  __shared__ __align__(16) _Float16 Wt[64*40];
  const int tid = threadIdx.x;
  const int wv = tid >> 6, lane = tid & 63, l15 = lane & 15, qd = lane >> 4;
  const int row0 = blockIdx.x * 64, col0 = blockIdx.y * 64;
  const int xr = tid >> 2, xc = (tid & 3) * 8;
  const int wk = tid >> 3, wc = (tid & 7) * 8;

  f32x4 acc[4] = {{0.f,0.f,0.f,0.f},{0.f,0.f,0.f,0.f},{0.f,0.f,0.f,0.f},{0.f,0.f,0.f,0.f}};

  for (int k0 = 0; k0 < 512; k0 += 32) {
    const size_t idx = (size_t)(row0 + xr)*512 + k0 + xc;
    half8 a0 = *(const half8*)(Ob + idx);
    half8 a1 = *(const half8*)(Ob + OPART + idx);
    *(half8*)&Xs[xr*40 + xc] = a0 + a1;
    f32x4 b0 = *(const f32x4*)(w + (size_t)(k0 + wk)*512 + col0 + wc);
    f32x4 b1 = *(const f32x4*)(w + (size_t)(k0 + wk)*512 + col0 + wc + 4);
#pragma unroll
    for (int j = 0; j < 4; j++) {
      Wt[(wc+j  )*40 + wk] = (_Float16)b0[j];
      Wt[(wc+j+4)*40 + wk] = (_Float16)b1[j];
    }
    __syncthreads();
    half8 af = *(const half8*)&Xs[(wv*16 + l15)*40 + qd*8];
#pragma unroll
    for (int ct = 0; ct < 4; ct++) {
      half8 bf = *(const half8*)&Wt[(ct*16 + l15)*40 + qd*8];
      acc[ct] = MFMA32(af, bf, acc[ct]);
    }
    __syncthreads();
  }
#pragma unroll
  for (int ct = 0; ct < 4; ct++) {
    const int c = col0 + ct*16 + l15;
    const float bv = bias[c];
#pragma unroll
    for (int i = 0; i < 4; i++) {
      const int row = row0 + wv*16 + qd*4 + i;
      out[(size_t)row*512 + c] = acc[ct][i] + bv;
    }
  }
}

// ---------------------------------------------------------------------------
extern "C" void kernel_launch(void* const* d_in, const int* in_sizes, int n_in,
                              void* d_out, int out_size, void* d_ws, size_t ws_size,
                              hipStream_t stream)
{
  (void)in_sizes; (void)n_in; (void)out_size;
  const float* x     = (const float*)d_in[0];
  const float* w_qkv = (const float*)d_in[1];
  const float* b_qkv = (const float*)d_in[2];
  const float* th1   = (const float*)d_in[3];
  const float* th2   = (const float*)d_in[4];
  const float* w_out = (const float*)d_in[5];
  const float* b_out = (const float*)d_in[6];
  float* out = (float*)d_out;

  char* ws = (char*)d_ws;
  _Float16* Qh   = (_Float16*)(ws + QH_OFF);
  _Float16* Kh   = (_Float16*)(ws + KH_OFF);
  _Float16* Vt   = (_Float16*)(ws + VT_OFF);
  float*    Lsum = (float*)   (ws + LS_OFF);
  _Float16* Obuf = (_Float16*)(ws + O_OFF);
  // Xf/Wtf alias the Obuf region (qkv consumes them before pass2 writes O)
  _Float16* Xf   = (_Float16*)(ws + O_OFF);
  _Float16* Wtf  = (_Float16*)(ws + O_OFF + ((size_t)8 << 20));
  if (ws_size < ((size_t)41 << 20)) return;  // need 41 MB scratch

  k_cvtx <<<dim3(4096),    256, 0, stream>>>(x, Xf);
  k_cvtw <<<dim3(16, 48),  256, 0, stream>>>(w_qkv, Wtf);
  k_qkv  <<<dim3(128, 24), 256, 0, stream>>>(Xf, Wtf, b_qkv, Qh, Kh, Vt);
  k_pass1<<<dim3(512),     512, 0, stream>>>(Qh, Kh, th1, Lsum);
  k_pass2<<<dim3(512),     512, 0, stream>>>(Qh, Kh, Vt, Lsum, th1, th2, Obuf);
  k_oproj<<<dim3(128, 8),  256, 0, stream>>>(Obuf, w_out, b_out, out);
}